// Round 13
// baseline (175.316 us; speedup 1.0000x reference)
//
#include <hip/hip_runtime.h>

// B=8, N=16384, E=64, F=64. Positions = B*N = 131072.
// Y[f, (p,i)] = sum_k Mcat[f][k] * T[p][k][i];  Mcat = [A|Bw|C], K=192.
// R13 = R9 exact bodies + Ys OVERLAYED on Tl storage (union, disjoint
// lifetimes enforced by barriers): LDS 30720 -> 18432 B = 8 blocks/CU
// (32 waves/CU cap, 2x R9's TLP). Cost: 4 barriers/unit instead of 2
// (A: Tl ready; B: Tl reads done; C: Ys ready; D: Ys reads done).
// R10 lesson: occupancy was LDS-pinned, not grid-pinned.
// R11 lesson: keep Ys staging + full-line dwordx4 stores.
// R12 lesson: keep R9's verified codegen (typed arrays, same swizzles).

#define NPOS   131072
#define PB     16            // positions per unit
#define NC     (PB * 3)      // 48 N-columns per unit
#define ITERS  4
#define BLOCKS (NPOS / (PB * ITERS))   // 2048 = 8 blocks/CU * 256 CU
#define THREADS 256          // 4 waves; wave w owns f-tile [16w,16w+16)
#define PPW    4             // positions per wave per unit

typedef _Float16 half8 __attribute__((ext_vector_type(8)));
typedef float floatx4 __attribute__((ext_vector_type(4)));

__global__ __launch_bounds__(THREADS, 4)
void fused_mfma(const float* __restrict__ X, const float* __restrict__ J,
                const float* __restrict__ A, const float* __restrict__ Bw,
                const float* __restrict__ Cm, float* __restrict__ Y) {
    // Single 18432B region, two logical views with disjoint lifetimes:
    //  Tl view: [6][NC][4][8] f16, kappa = ks*32+kg*8+j, kg XOR-swizzled by
    //           ((n>>1)&3) (R4-verified 0-conflict b128 reads).
    //  Ys view: PB*192 f32 (12288B), 16B chunks XOR-permuted
    //           c' = c ^ ((c>>4)&15) (R7/R8-verified).
    __shared__ __align__(16) char ldsbuf[6 * NC * 4 * 8 * 2];   // 18432 B
    _Float16* TlF = (_Float16*)ldsbuf;
    float*    Ys  = (float*)ldsbuf;
#define TL(ks, n, kg, j) TlF[((((ks) * NC + (n)) * 4 + (kg)) * 8 + (j))]

    const int lane = threadIdx.x & 63;
    const int w    = threadIdx.x >> 6;
    const int tid  = threadIdx.x;

    // ---- Mcat fragments in registers for the whole kernel (6 frags/wave).
    // lane holds Mcat[f = 16w+(l&15)][k = ks*32 + (l>>4)*8 + j], j=0..7.
    const int fa  = w * 16 + (lane & 15);
    const int kgA = lane >> 4;
    half8 afrag[6];
    #pragma unroll
    for (int ks = 0; ks < 6; ++ks) {
        const float* mat = (ks < 2) ? A : (ks < 4 ? Bw : Cm);
        const float* src = mat + fa * 64 + (ks & 1) * 32 + kgA * 8;
        float4 lo = *(const float4*)src;
        float4 hi = *(const float4*)(src + 4);
        half8 h;
        h[0] = (_Float16)lo.x; h[1] = (_Float16)lo.y;
        h[2] = (_Float16)lo.z; h[3] = (_Float16)lo.w;
        h[4] = (_Float16)hi.x; h[5] = (_Float16)hi.y;
        h[6] = (_Float16)hi.z; h[7] = (_Float16)hi.w;
        afrag[ks] = h;
    }

    // P1 write coords (e = lane): ks = 2t + (e>>5), kg = (e&31)>>3, j = e&7.
    const int ks0 = lane >> 5;
    const int kgW = (lane & 31) >> 3;
    const int jW  = lane & 7;
    // P2 read kg slot (swizzle-corrected; nt-independent: nt*16 % 4 == 0).
    const int kgR = (lane >> 4) ^ (((lane & 15) >> 1) & 3);
    const int nR  = lane & 15;

    // Two named prefetch buffers (static indexing only — R4/R8 spill lesson).
    float jrA[PPW][3], xrA[PPW][3], jrB[PPW][3], xrB[PPW][3];
    // Accumulators live across barrier B (named, static).
    floatx4 acc0, acc1, acc2;

#define LOAD_BODY(JR, XR, T)                                                  \
    {                                                                         \
        _Pragma("unroll")                                                     \
        for (int q = 0; q < PPW; ++q) {                                       \
            const int p = (blockIdx.x * ITERS + (T)) * PB + w * PPW + q;      \
            const float* jp = J + (size_t)(p * 64 + lane) * 3;                \
            const float* xp = X + (size_t)(p * 64 + lane) * 3;                \
            JR[q][0] = jp[0]; JR[q][1] = jp[1]; JR[q][2] = jp[2];             \
            XR[q][0] = xp[0]; XR[q][1] = xp[1]; XR[q][2] = xp[2];             \
        }                                                                     \
    }

#define P1_BODY(JR, XR)                                                       \
    {                                                                         \
        _Pragma("unroll")                                                     \
        for (int q = 0; q < PPW; ++q) {                                       \
            const int p_local = w * PPW + q;                                  \
            float ja = JR[q][0], jb = JR[q][1], jg = JR[q][2];                \
            float x0 = XR[q][0], x1 = XR[q][1], x2 = XR[q][2];                \
            float sa, ca, sb, cb, sg, cg;                                     \
            __sincosf(ja, &sa, &ca);                                          \
            __sincosf(jb, &sb, &cb);                                          \
            __sincosf(jg, &sg, &cg);                                          \
            float casb = ca * sb, sasb = sa * sb;                             \
            float r00 = ca * cb, r01 = casb * sg - sa * cg;                   \
            float r02 = casb * cg + sa * sg;                                  \
            float r10 = sa * cb, r11 = sasb * sg + ca * cg;                   \
            float r12 = sasb * cg - ca * sg;                                  \
            float r20 = -sb, r21 = cb * sg, r22 = cb * cg;                    \
            float v0 = fmaf(r00, x0, fmaf(r10, x1, r20 * x2));                \
            float v1 = fmaf(r01, x0, fmaf(r11, x1, r21 * x2));                \
            float v2 = fmaf(r02, x0, fmaf(r12, x1, r22 * x2));                \
            float ta[3], tb[3], tc[3];                                        \
            ta[0] = fmaf(r00, v0, r01 * v1);                                  \
            ta[1] = fmaf(r10, v0, r11 * v1);                                  \
            ta[2] = fmaf(r20, v0, r21 * v1);                                  \
            tb[0] = fmaf(r01, v0, -r00 * v1);                                 \
            tb[1] = fmaf(r11, v0, -r10 * v1);                                 \
            tb[2] = fmaf(r21, v0, -r20 * v1);                                 \
            tc[0] = r02 * v2; tc[1] = r12 * v2; tc[2] = r22 * v2;             \
            _Pragma("unroll")                                                 \
            for (int i = 0; i < 3; ++i) {                                     \
                const int n  = p_local * 3 + i;                               \
                const int kg = kgW ^ ((n >> 1) & 3);                          \
                TL(0 + ks0, n, kg, jW) = (_Float16)ta[i];                     \
                TL(2 + ks0, n, kg, jW) = (_Float16)tb[i];                     \
                TL(4 + ks0, n, kg, jW) = (_Float16)tc[i];                     \
            }                                                                 \
        }                                                                     \
    }

// P2R: MFMA over K=192 into named acc0..2 (no LDS writes).
#define P2R_BODY()                                                            \
    {                                                                         \
        acc0 = (floatx4){0.f, 0.f, 0.f, 0.f};                                 \
        acc1 = (floatx4){0.f, 0.f, 0.f, 0.f};                                 \
        acc2 = (floatx4){0.f, 0.f, 0.f, 0.f};                                 \
        _Pragma("unroll")                                                     \
        for (int ks = 0; ks < 6; ++ks) {                                      \
            half8 b0 = *(const half8*)&TL(ks,  0 + nR, kgR, 0);               \
            half8 b1 = *(const half8*)&TL(ks, 16 + nR, kgR, 0);               \
            half8 b2 = *(const half8*)&TL(ks, 32 + nR, kgR, 0);               \
            acc0 = __builtin_amdgcn_mfma_f32_16x16x32_f16(afrag[ks], b0, acc0, 0, 0, 0); \
            acc1 = __builtin_amdgcn_mfma_f32_16x16x32_f16(afrag[ks], b1, acc1, 0, 0, 0); \
            acc2 = __builtin_amdgcn_mfma_f32_16x16x32_f16(afrag[ks], b2, acc2, 0, 0, 0); \
        }                                                                     \
    }

// P2W: stage acc -> Ys (overlay region; runs after barrier B).
#define YS_WRITE(ACC, NT)                                                     \
    {                                                                         \
        const int n   = (NT) * 16 + nR;                                       \
        const int pl2 = (n * 171) >> 9;   /* n/3 for n < 96 */                \
        const int i2  = n - pl2 * 3;                                          \
        const int fb  = w * 16 + (lane >> 4) * 4;                             \
        _Pragma("unroll")                                                     \
        for (int r = 0; r < 4; ++r) {                                         \
            const int z  = pl2 * 192 + (fb + r) * 3 + i2;                     \
            const int c  = z >> 2;                                            \
            const int zp = ((c ^ ((c >> 4) & 15)) << 2) | (z & 3);            \
            Ys[zp] = ACC[r];                                                  \
        }                                                                     \
    }

#define P2W_BODY()                                                            \
    {                                                                         \
        YS_WRITE(acc0, 0)                                                     \
        YS_WRITE(acc1, 1)                                                     \
        YS_WRITE(acc2, 2)                                                     \
    }

#define STORE_BODY(T)                                                         \
    {                                                                         \
        float* yb = Y + (size_t)(blockIdx.x * ITERS + (T)) * PB * 192;        \
        _Pragma("unroll")                                                     \
        for (int k = 0; k < 3; ++k) {                                         \
            const int c  = tid + 256 * k;                                     \
            const int cp = c ^ ((c >> 4) & 15);                               \
            floatx4 v = *(const floatx4*)&Ys[cp * 4];                         \
            __builtin_nontemporal_store(v, (floatx4*)(yb + (size_t)c * 4));   \
        }                                                                     \
    }

    // ---- Pipeline: 4 barriers/unit (overlay discipline), loads 2 units ahead.
    LOAD_BODY(jrA, xrA, 0);
    LOAD_BODY(jrB, xrB, 1);
    P1_BODY(jrA, xrA);                             // Tl for t=0
    for (int m = 0; m < ITERS / 2; ++m) {
        // ---- t = 2m (even slot; prefetch into A)
        __syncthreads();                           // A: Tl(t) ready
        if (m < ITERS / 2 - 1) LOAD_BODY(jrA, xrA, 2 * m + 2);
        P2R_BODY();                                // read Tl, MFMA -> acc
        __syncthreads();                           // B: all Tl reads done
        P2W_BODY();                                // write Ys (overlay)
        __syncthreads();                           // C: Ys ready
        STORE_BODY(2 * m);                         // coalesced nt stores
        __syncthreads();                           // D: Ys reads done
        P1_BODY(jrB, xrB);                         // Tl for t+1 (consumes B)
        // ---- t = 2m+1 (odd slot; prefetch into B)
        __syncthreads();                           // A
        if (m < ITERS / 2 - 1) LOAD_BODY(jrB, xrB, 2 * m + 3);
        P2R_BODY();
        __syncthreads();                           // B
        P2W_BODY();
        __syncthreads();                           // C
        STORE_BODY(2 * m + 1);
        if (m < ITERS / 2 - 1) {
            __syncthreads();                       // D
            P1_BODY(jrA, xrA);                     // Tl for t+2 (consumes A)
        }
    }
#undef LOAD_BODY
#undef P1_BODY
#undef P2R_BODY
#undef P2W_BODY
#undef YS_WRITE
#undef STORE_BODY
#undef TL
}

extern "C" void kernel_launch(void* const* d_in, const int* in_sizes, int n_in,
                              void* d_out, int out_size, void* d_ws, size_t ws_size,
                              hipStream_t stream) {
    const float* X  = (const float*)d_in[0];
    const float* J  = (const float*)d_in[1];
    const float* A  = (const float*)d_in[2];
    const float* Bw = (const float*)d_in[3];
    const float* Cm = (const float*)d_in[4];
    float* Y = (float*)d_out;
    fused_mfma<<<BLOCKS, THREADS, 0, stream>>>(X, J, A, Bw, Cm, Y);
}

// Round 14
// 53.586 us; speedup vs baseline: 3.2716x; 3.2716x over previous
//
#include <hip/hip_runtime.h>

// B=8, N=16384, E=64, F=64. Positions = B*N = 131072.
// Y[f, (p,i)] = sum_{k=0..191} Mcat[f][k] * T[p][k][i];  Mcat = [A|Bw|C].
// R14 = R9 VERBATIM (best: 53.6us). Post-R13 understanding: the AMDGPU
// backend derives its VGPR cap from LDS-implied occupancy (18KB LDS ->
// 8 blocks/CU -> 64-VGPR cap -> spills). R9's 30.7KB LDS keeps the
// compiler at 5 blocks/CU target -> ~102 VGPR budget -> VGPR 60, no spill.
// Failed levers (R10-R13): grid-residency null; direct scattered stores
// -73% (transaction-bound); LDS-write vectorization codegen regression;
// LDS overlay spill trap. Keep: Tl kg-XOR swizzle (0-conflict b128 reads),
// Ys chunk-XOR staging + full-line dwordx4 nt stores, 2-deep register
// prefetch, 2 barriers/unit, 1024 blocks x ITERS 8.

#define NPOS   131072
#define PB     16            // positions per block-iteration
#define NC     (PB * 3)      // 48 N-columns per iteration
#define ITERS  8
#define BLOCKS (NPOS / (PB * ITERS))   // 1024
#define THREADS 256          // 4 waves; wave w owns f-tile [16w,16w+16)
#define PPW    4             // positions per wave per iteration

typedef _Float16 half8 __attribute__((ext_vector_type(8)));
typedef float floatx4 __attribute__((ext_vector_type(4)));

__global__ __launch_bounds__(THREADS, 4)
void fused_mfma(const float* __restrict__ X, const float* __restrict__ J,
                const float* __restrict__ A, const float* __restrict__ Bw,
                const float* __restrict__ Cm, float* __restrict__ Y) {
    // Terms: kappa = ks*32 + kg*8 + j, kg slot XOR-swizzled by ((n>>1)&3)
    // (R4-verified 0-conflict reads).
    __shared__ _Float16 Tl[6][NC][4][8];     // 18432 B
    // Y staging: logical = block's contiguous 12288B Y slice; physical 16B
    // chunks XOR-permuted c' = c ^ ((c>>4)&15) (involution within 256B).
    __shared__ float Ys[PB * 192];           // 12288 B   (total 30720 B)

    const int lane = threadIdx.x & 63;
    const int w    = threadIdx.x >> 6;
    const int tid  = threadIdx.x;

    // ---- Mcat fragments in registers for the whole kernel (6 frags/wave).
    // lane holds Mcat[f = 16w+(l&15)][k = ks*32 + (l>>4)*8 + j], j=0..7.
    const int fa  = w * 16 + (lane & 15);
    const int kgA = lane >> 4;
    half8 afrag[6];
    #pragma unroll
    for (int ks = 0; ks < 6; ++ks) {
        const float* mat = (ks < 2) ? A : (ks < 4 ? Bw : Cm);
        const float* src = mat + fa * 64 + (ks & 1) * 32 + kgA * 8;
        float4 lo = *(const float4*)src;
        float4 hi = *(const float4*)(src + 4);
        half8 h;
        h[0] = (_Float16)lo.x; h[1] = (_Float16)lo.y;
        h[2] = (_Float16)lo.z; h[3] = (_Float16)lo.w;
        h[4] = (_Float16)hi.x; h[5] = (_Float16)hi.y;
        h[6] = (_Float16)hi.z; h[7] = (_Float16)hi.w;
        afrag[ks] = h;
    }

    // P1 write coords (e = lane): ks = 2t + (e>>5), kg = (e&31)>>3, j = e&7.
    const int ks0 = lane >> 5;
    const int kgW = (lane & 31) >> 3;
    const int jW  = lane & 7;
    // P2 B-frag read slot (swizzle-corrected; nt-independent: nt*16 % 4 == 0).
    const int kgR = (lane >> 4) ^ (((lane & 15) >> 1) & 3);

    // Two named prefetch buffers (static indexing only — R4/R8 spill lesson).
    float jrA[PPW][3], xrA[PPW][3], jrB[PPW][3], xrB[PPW][3];

#define LOAD_BODY(JR, XR, T)                                                  \
    {                                                                         \
        _Pragma("unroll")                                                     \
        for (int q = 0; q < PPW; ++q) {                                       \
            const int p = (blockIdx.x * ITERS + (T)) * PB + w * PPW + q;      \
            const float* jp = J + (size_t)(p * 64 + lane) * 3;                \
            const float* xp = X + (size_t)(p * 64 + lane) * 3;                \
            JR[q][0] = jp[0]; JR[q][1] = jp[1]; JR[q][2] = jp[2];             \
            XR[q][0] = xp[0]; XR[q][1] = xp[1]; XR[q][2] = xp[2];             \
        }                                                                     \
    }

#define P1_BODY(JR, XR)                                                       \
    {                                                                         \
        _Pragma("unroll")                                                     \
        for (int q = 0; q < PPW; ++q) {                                       \
            const int p_local = w * PPW + q;                                  \
            float ja = JR[q][0], jb = JR[q][1], jg = JR[q][2];                \
            float x0 = XR[q][0], x1 = XR[q][1], x2 = XR[q][2];                \
            float sa, ca, sb, cb, sg, cg;                                     \
            __sincosf(ja, &sa, &ca);                                          \
            __sincosf(jb, &sb, &cb);                                          \
            __sincosf(jg, &sg, &cg);                                          \
            float casb = ca * sb, sasb = sa * sb;                             \
            float r00 = ca * cb, r01 = casb * sg - sa * cg;                   \
            float r02 = casb * cg + sa * sg;                                  \
            float r10 = sa * cb, r11 = sasb * sg + ca * cg;                   \
            float r12 = sasb * cg - ca * sg;                                  \
            float r20 = -sb, r21 = cb * sg, r22 = cb * cg;                    \
            float v0 = fmaf(r00, x0, fmaf(r10, x1, r20 * x2));                \
            float v1 = fmaf(r01, x0, fmaf(r11, x1, r21 * x2));                \
            float v2 = fmaf(r02, x0, fmaf(r12, x1, r22 * x2));                \
            float ta[3], tb[3], tc[3];                                        \
            ta[0] = fmaf(r00, v0, r01 * v1);                                  \
            ta[1] = fmaf(r10, v0, r11 * v1);                                  \
            ta[2] = fmaf(r20, v0, r21 * v1);                                  \
            tb[0] = fmaf(r01, v0, -r00 * v1);                                 \
            tb[1] = fmaf(r11, v0, -r10 * v1);                                 \
            tb[2] = fmaf(r21, v0, -r20 * v1);                                 \
            tc[0] = r02 * v2; tc[1] = r12 * v2; tc[2] = r22 * v2;             \
            _Pragma("unroll")                                                 \
            for (int i = 0; i < 3; ++i) {                                     \
                const int n  = p_local * 3 + i;                               \
                const int kg = kgW ^ ((n >> 1) & 3);                          \
                Tl[0 + ks0][n][kg][jW] = (_Float16)ta[i];                     \
                Tl[2 + ks0][n][kg][jW] = (_Float16)tb[i];                     \
                Tl[4 + ks0][n][kg][jW] = (_Float16)tc[i];                     \
            }                                                                 \
        }                                                                     \
    }

#define P2_BODY()                                                             \
    {                                                                         \
        _Pragma("unroll")                                                     \
        for (int nt = 0; nt < 3; ++nt) {                                      \
            floatx4 acc = {0.f, 0.f, 0.f, 0.f};                               \
            _Pragma("unroll")                                                 \
            for (int ks = 0; ks < 6; ++ks) {                                  \
                half8 b = *(const half8*)&Tl[ks][nt * 16 + (lane & 15)][kgR][0]; \
                acc = __builtin_amdgcn_mfma_f32_16x16x32_f16(afrag[ks], b, acc, 0, 0, 0); \
            }                                                                 \
            const int n   = nt * 16 + (lane & 15);                            \
            const int pl2 = (n * 171) >> 9;   /* n/3 for n < 96 */            \
            const int i2  = n - pl2 * 3;                                      \
            const int fb  = w * 16 + (lane >> 4) * 4;                         \
            _Pragma("unroll")                                                 \
            for (int r = 0; r < 4; ++r) {                                     \
                const int z  = pl2 * 192 + (fb + r) * 3 + i2;                 \
                const int c  = z >> 2;                                        \
                const int zp = ((c ^ ((c >> 4) & 15)) << 2) | (z & 3);        \
                Ys[zp] = acc[r];                                              \
            }                                                                 \
        }                                                                     \
    }

#define STORE_BODY(T)                                                         \
    {                                                                         \
        float* yb = Y + (size_t)(blockIdx.x * ITERS + (T)) * PB * 192;        \
        _Pragma("unroll")                                                     \
        for (int k = 0; k < 3; ++k) {                                         \
            const int c  = tid + 256 * k;                                     \
            const int cp = c ^ ((c >> 4) & 15);                               \
            floatx4 v = *(const floatx4*)&Ys[cp * 4];                         \
            __builtin_nontemporal_store(v, (floatx4*)(yb + (size_t)c * 4));   \
        }                                                                     \
    }

    // ---- Pipeline: 2 barriers/iter, loads 2 iterations ahead.
    LOAD_BODY(jrA, xrA, 0);
    LOAD_BODY(jrB, xrB, 1);
    P1_BODY(jrA, xrA);                         // Tl for t=0
    for (int m = 0; m < ITERS / 2; ++m) {
        // ---- t = 2m (even slot; prefetch into A)
        __syncthreads();                       // Tl(t) visible
        if (m < ITERS / 2 - 1) LOAD_BODY(jrA, xrA, 2 * m + 2);
        P2_BODY();
        __syncthreads();                       // Ys visible; Tl reads done
        STORE_BODY(2 * m);
        P1_BODY(jrB, xrB);                     // Tl for t+1 (consumes B)
        // ---- t = 2m+1 (odd slot; prefetch into B)
        __syncthreads();
        if (m < ITERS / 2 - 1) LOAD_BODY(jrB, xrB, 2 * m + 3);
        P2_BODY();
        __syncthreads();
        STORE_BODY(2 * m + 1);
        if (m < ITERS / 2 - 1) P1_BODY(jrA, xrA);   // Tl for t+2 (consumes A)
    }
#undef LOAD_BODY
#undef P1_BODY
#undef P2_BODY
#undef STORE_BODY
}

extern "C" void kernel_launch(void* const* d_in, const int* in_sizes, int n_in,
                              void* d_out, int out_size, void* d_ws, size_t ws_size,
                              hipStream_t stream) {
    const float* X  = (const float*)d_in[0];
    const float* J  = (const float*)d_in[1];
    const float* A  = (const float*)d_in[2];
    const float* Bw = (const float*)d_in[3];
    const float* Cm = (const float*)d_in[4];
    float* Y = (float*)d_out;
    fused_mfma<<<BLOCKS, THREADS, 0, stream>>>(X, J, A, Bw, Cm, Y);
}